// Round 7
// baseline (310.263 us; speedup 1.0000x reference)
//
#include <hip/hip_runtime.h>
#include <hip/hip_bf16.h>
#include <math.h>

constexpr int B_  = 4;
constexpr int S_  = 1024;
constexpr int D_  = 512;
constexpr int H_  = 8;
constexpr int DK_ = 64;
constexpr int MROWS_ = B_ * S_;          // 4096
constexpr size_t SZ_ = (size_t)B_ * H_ * S_ * DK_;  // 2M elems per tensor
constexpr size_t WSZ_ = (size_t)D_ * D_;            // 256K elems per weight

typedef __attribute__((ext_vector_type(8))) short bf16x8;
typedef __attribute__((ext_vector_type(4))) float f32x4;

__device__ __forceinline__ float bf2f(unsigned short u) {
  union { unsigned int u; float f; } v; v.u = (unsigned int)u << 16; return v.f;
}
__device__ __forceinline__ unsigned short f2bf(float f) {
  union { float f; unsigned int u; } v; v.f = f;
  unsigned int r = v.u + 0x7FFFu + ((v.u >> 16) & 1u);   // RNE
  return (unsigned short)(r >> 16);
}

// ---- DPP cross-lane helpers (VALU pipe, no LDS) ----
template <int CTRL>
__device__ __forceinline__ float dpp_mov_f(float x) {
  return __builtin_bit_cast(float,
      __builtin_amdgcn_update_dpp(0, __builtin_bit_cast(int, x), CTRL, 0xF, 0xF, true));
}
__device__ __forceinline__ float scan16(float v) {
  v += dpp_mov_f<0x111>(v);   // row_shr:1
  v += dpp_mov_f<0x112>(v);   // row_shr:2
  v += dpp_mov_f<0x114>(v);   // row_shr:4
  v += dpp_mov_f<0x118>(v);   // row_shr:8
  return v;
}
__device__ __forceinline__ float red16(float v) {
  v += dpp_mov_f<0x128>(v);   // row_ror:8
  v += dpp_mov_f<0x124>(v);   // row_ror:4
  v += dpp_mov_f<0x122>(v);   // row_ror:2
  v += dpp_mov_f<0x121>(v);   // row_ror:1
  return v;
}
// broadcast lane15 of each 16-lane group
__device__ __forceinline__ float bcast15(float v) {
  return __builtin_bit_cast(float,
      __builtin_amdgcn_ds_swizzle(__builtin_bit_cast(int, v), 0x01F0));
}

// ---------------------------------------------------------------------------
// W transpose+convert (unchanged).
// ---------------------------------------------------------------------------
struct TpArgs { const float* W[4]; unsigned short* out[4]; };

__global__ __launch_bounds__(256) void wtrans(TpArgs a) {
  const int z = blockIdx.z;
  const float* __restrict__ W = a.W[z];
  unsigned short* __restrict__ out = a.out[z];
  __shared__ float T[64][65];
  const int tid = threadIdx.x;
  const int tx = blockIdx.x & 7, ty = blockIdx.x >> 3;
  const int k0 = ty * 64, n0 = tx * 64;
#pragma unroll
  for (int i = 0; i < 4; ++i) {
    const int idx = tid + i * 256;
    const int r = idx >> 4, c4 = (idx & 15) * 4;
    const float4 w = *(const float4*)&W[(size_t)(k0 + r) * D_ + n0 + c4];
    T[r][c4 + 0] = w.x; T[r][c4 + 1] = w.y; T[r][c4 + 2] = w.z; T[r][c4 + 3] = w.w;
  }
  __syncthreads();
#pragma unroll
  for (int i = 0; i < 4; ++i) {
    const int idx = tid + i * 256;
    const int n = idx >> 4, kc = (idx & 15) * 4;
    ushort4 pk;
    pk.x = f2bf(T[kc + 0][n]); pk.y = f2bf(T[kc + 1][n]);
    pk.z = f2bf(T[kc + 2][n]); pk.w = f2bf(T[kc + 3][n]);
    *(ushort4*)&out[(size_t)(n0 + n) * D_ + k0 + kc] = pk;
  }
}

// ---------------------------------------------------------------------------
// MFMA projection GEMM. NEW: per-z output scale (folds 1/sqrt(DK) into Q).
// ---------------------------------------------------------------------------
struct ProjArgs {
  const float* A[6]; const unsigned short* Wt[6]; const float* bias[6];
  unsigned short* out[6]; int vmode[6]; float scale[6];
};

__global__ __launch_bounds__(256) void proj_mfma(ProjArgs args) {
  const int z = blockIdx.z;
  const float* __restrict__ A = args.A[z];
  const unsigned short* __restrict__ Wt = args.Wt[z];
  const float* __restrict__ bias = args.bias[z];
  unsigned short* __restrict__ out = args.out[z];
  const int vmode = args.vmode[z];
  const float scale = args.scale[z];

  __shared__ unsigned short Abuf[128][40];
  __shared__ unsigned short Bbuf[128][40];
  const int tid = threadIdx.x, wv = tid >> 6, lane = tid & 63;
  const int quad = lane >> 4, l16 = lane & 15;
  const int wm = wv >> 1, wn = wv & 1;
  const int n0 = blockIdx.x * 128, m0 = blockIdx.y * 128;

  f32x4 acc[4][4];
#pragma unroll
  for (int i = 0; i < 4; ++i)
#pragma unroll
    for (int j = 0; j < 4; ++j) acc[i][j] = (f32x4){0.f, 0.f, 0.f, 0.f};

  for (int kt = 0; kt < 16; ++kt) {
    const int k0 = kt * 32;
    __syncthreads();
#pragma unroll
    for (int i = 0; i < 4; ++i) {
      const int idx = tid + i * 256;
      const int m = idx >> 3, c = idx & 7;
      const float4 av = *(const float4*)&A[(size_t)(m0 + m) * D_ + k0 + c * 4];
      ushort4 p;
      p.x = f2bf(av.x); p.y = f2bf(av.y); p.z = f2bf(av.z); p.w = f2bf(av.w);
      *(ushort4*)&Abuf[m][c * 4] = p;
    }
#pragma unroll
    for (int i = 0; i < 2; ++i) {
      const int idx = tid + i * 256;
      const int n = idx >> 2, c = idx & 3;
      *(uint4*)&Bbuf[n][c * 8] = *(const uint4*)&Wt[(size_t)(n0 + n) * D_ + k0 + c * 8];
    }
    __syncthreads();

    bf16x8 af[4], bfr[4];
#pragma unroll
    for (int i = 0; i < 4; ++i) af[i] = *(const bf16x8*)&Abuf[wm * 64 + i * 16 + l16][quad * 8];
#pragma unroll
    for (int j = 0; j < 4; ++j) bfr[j] = *(const bf16x8*)&Bbuf[wn * 64 + j * 16 + l16][quad * 8];
#pragma unroll
    for (int i = 0; i < 4; ++i)
#pragma unroll
      for (int j = 0; j < 4; ++j)
        acc[i][j] = __builtin_amdgcn_mfma_f32_16x16x32_bf16(af[i], bfr[j], acc[i][j], 0, 0, 0);
  }

#pragma unroll
  for (int j = 0; j < 4; ++j) {
    const int col = n0 + wn * 64 + j * 16 + l16;
    const float bv = bias[col];
    const int h = col >> 6, dk = col & 63;
#pragma unroll
    for (int i = 0; i < 4; ++i) {
      const int mbase = m0 + wm * 64 + i * 16 + quad * 4;
      const int b = mbase >> 10;
      if (!vmode) {
#pragma unroll
        for (int r = 0; r < 4; ++r) {
          const int s = (mbase + r) & 1023;
          out[(((size_t)b * H_ + h) * S_ + s) * DK_ + dk] = f2bf((acc[i][j][r] + bv) * scale);
        }
      } else {
        const int s = mbase & 1023;
        ushort4 pk;
        pk.x = f2bf(acc[i][j][0] + bv); pk.y = f2bf(acc[i][j][1] + bv);
        pk.z = f2bf(acc[i][j][2] + bv); pk.w = f2bf(acc[i][j][3] + bv);
        *(ushort4*)&out[(((size_t)b * H_ + h) * DK_ + dk) * S_ + s] = pk;
      }
    }
  }
}

// ---------------------------------------------------------------------------
// MFMA output GEMM (unchanged).
// ---------------------------------------------------------------------------
struct OutArgs {
  const unsigned short* A[2]; const unsigned short* Wt[2];
  const float* bias[2]; float* out[2];
};

__global__ __launch_bounds__(256) void out_mfma(OutArgs args) {
  const int z = blockIdx.z;
  const unsigned short* __restrict__ A = args.A[z];
  const unsigned short* __restrict__ Wt = args.Wt[z];
  const float* __restrict__ bias = args.bias[z];
  float* __restrict__ out = args.out[z];

  __shared__ unsigned short Abuf[128][40];
  __shared__ unsigned short Bbuf[128][40];
  const int tid = threadIdx.x, wv = tid >> 6, lane = tid & 63;
  const int quad = lane >> 4, l16 = lane & 15;
  const int wm = wv >> 1, wn = wv & 1;
  const int n0 = blockIdx.x * 128, m0 = blockIdx.y * 128;

  f32x4 acc[4][4];
#pragma unroll
  for (int i = 0; i < 4; ++i)
#pragma unroll
    for (int j = 0; j < 4; ++j) acc[i][j] = (f32x4){0.f, 0.f, 0.f, 0.f};

  for (int kt = 0; kt < 16; ++kt) {
    const int k0 = kt * 32;
    __syncthreads();
#pragma unroll
    for (int i = 0; i < 2; ++i) {
      const int idx = tid + i * 256;
      const int m = idx >> 2, c = idx & 3;
      *(uint4*)&Abuf[m][c * 8] = *(const uint4*)&A[(size_t)(m0 + m) * D_ + k0 + c * 8];
    }
#pragma unroll
    for (int i = 0; i < 2; ++i) {
      const int idx = tid + i * 256;
      const int n = idx >> 2, c = idx & 3;
      *(uint4*)&Bbuf[n][c * 8] = *(const uint4*)&Wt[(size_t)(n0 + n) * D_ + k0 + c * 8];
    }
    __syncthreads();

    bf16x8 af[4], bfr[4];
#pragma unroll
    for (int i = 0; i < 4; ++i) af[i] = *(const bf16x8*)&Abuf[wm * 64 + i * 16 + l16][quad * 8];
#pragma unroll
    for (int j = 0; j < 4; ++j) bfr[j] = *(const bf16x8*)&Bbuf[wn * 64 + j * 16 + l16][quad * 8];
#pragma unroll
    for (int i = 0; i < 4; ++i)
#pragma unroll
      for (int j = 0; j < 4; ++j)
        acc[i][j] = __builtin_amdgcn_mfma_f32_16x16x32_bf16(af[i], bfr[j], acc[i][j], 0, 0, 0);
  }

#pragma unroll
  for (int j = 0; j < 4; ++j) {
    const int col = n0 + wn * 64 + j * 16 + l16;
    const float bv = bias[col];
#pragma unroll
    for (int i = 0; i < 4; ++i) {
      const int mbase = m0 + wm * 64 + i * 16 + quad * 4;
#pragma unroll
      for (int r = 0; r < 4; ++r)
        out[(size_t)(mbase + r) * D_ + col] = acc[i][j][r] + bv;
    }
  }
}

// ---------------------------------------------------------------------------
// R7 attention: 32-row waves, single-wave 64-thread blocks.
// Wave owns rows [32G, 32G+32) = two 16-row MFMA subtiles sharing one
// K/V fragment stream (loads+addresses amortized 2x, two independent
// dependency chains per wave for latency cover). No barriers, no LDS
// except the per-wave P relayout (4.6 KB). Q pre-scaled by 1/8 in proj.
// Grid (bh=32, G=32 heavy-first, ch=2) = 2048 blocks x 64 thr.
// ---------------------------------------------------------------------------
__global__ __launch_bounds__(64) void attn_mfma(
    const unsigned short* __restrict__ qkv, const float* __restrict__ gammas,
    unsigned short* __restrict__ Obase)
{
  __shared__ unsigned short Ps[32][72];   // P relayout, rows 0-15 sub0, 16-31 sub1

  const int lane = threadIdx.x, quad = lane >> 4, l16 = lane & 15;
  const int G  = 31 - blockIdx.y;          // 32-row group, heavy first
  const int bh = blockIdx.x;
  const int ch = blockIdx.z;
  const int b = bh >> 3, h = bh & 7;
  const int nc = (G >> 1) + 1;             // 64-key chunks
  const int row0 = G * 32;

  const unsigned short* Q  = qkv + (size_t)ch * 3 * SZ_ + (size_t)bh * S_ * DK_;
  const unsigned short* K  = qkv + (size_t)ch * 3 * SZ_ + SZ_ + (size_t)bh * S_ * DK_;
  const unsigned short* Vt = qkv + (size_t)ch * 3 * SZ_ + 2 * SZ_ + (size_t)bh * (size_t)DK_ * S_;
  unsigned short* O = Obase + (size_t)ch * SZ_;

  const float g0 = gammas[h];
  const float gv = -(fmaxf(g0, 0.f) + log1pf(__expf(-fabsf(g0))));  // -softplus

  // Q fragments for both subtiles (Q pre-scaled by 1/8)
  const unsigned short* Qr0 = Q + (size_t)(row0 + l16) * DK_;
  const unsigned short* Qr1 = Q + (size_t)(row0 + 16 + l16) * DK_;
  const bf16x8 qfa0 = *(const bf16x8*)(Qr0 + quad * 8);
  const bf16x8 qfa1 = *(const bf16x8*)(Qr0 + 32 + quad * 8);
  const bf16x8 qfb0 = *(const bf16x8*)(Qr1 + quad * 8);
  const bf16x8 qfb1 = *(const bf16x8*)(Qr1 + 32 + quad * 8);
  const int myrow0 = row0 + quad * 4;        // + r  (sub0)
  const int myrow1 = row0 + 16 + quad * 4;   // + r  (sub1)

  // ===== pass A: T = sum exp(s) per row, both subtiles =====
  float Ta[2][4] = {{0.f}};
  for (int c = 0; c < nc; ++c) {
    const bool last = (c == nc - 1);
#pragma unroll
    for (int cb = 0; cb < 4; ++cb) {
      const unsigned short* Kr = K + (size_t)(c * 64 + cb * 16 + l16) * DK_;
      const bf16x8 kf0 = *(const bf16x8*)(Kr + quad * 8);
      const bf16x8 kf1 = *(const bf16x8*)(Kr + 32 + quad * 8);
      f32x4 s0 = {0.f, 0.f, 0.f, 0.f}, s1 = {0.f, 0.f, 0.f, 0.f};
      s0 = __builtin_amdgcn_mfma_f32_16x16x32_bf16(qfa0, kf0, s0, 0, 0, 0);
      s0 = __builtin_amdgcn_mfma_f32_16x16x32_bf16(qfa1, kf1, s0, 0, 0, 0);
      s1 = __builtin_amdgcn_mfma_f32_16x16x32_bf16(qfb0, kf0, s1, 0, 0, 0);
      s1 = __builtin_amdgcn_mfma_f32_16x16x32_bf16(qfb1, kf1, s1, 0, 0, 0);
      const int key = c * 64 + cb * 16 + l16;
#pragma unroll
      for (int r = 0; r < 4; ++r) {
        float e0 = __expf(s0[r]);
        float e1 = __expf(s1[r]);
        if (last && key > (myrow0 + r)) e0 = 0.f;
        if (last && key > (myrow1 + r)) e1 = 0.f;
        Ta[0][r] += e0; Ta[1][r] += e1;
      }
    }
  }
  float invT[2][4];
#pragma unroll
  for (int t = 0; t < 2; ++t)
#pragma unroll
    for (int r = 0; r < 4; ++r) invT[t][r] = 1.f / red16(Ta[t][r]);

  // ===== pass B =====
  float carry[2][4] = {{0.f}};
  float l2a[2][4] = {{0.f}};
  f32x4 oacc[2][4];
#pragma unroll
  for (int t = 0; t < 2; ++t)
#pragma unroll
    for (int cb = 0; cb < 4; ++cb) oacc[t][cb] = (f32x4){0.f, 0.f, 0.f, 0.f};

  for (int c = 0; c < nc; ++c) {
    const bool last = (c == nc - 1);
    // shared V fragments (consumed at iteration end)
    bf16x8 vf0[4], vf1[4];
#pragma unroll
    for (int cb = 0; cb < 4; ++cb) {
      const unsigned short* Vr = Vt + (size_t)(cb * 16 + l16) * S_ + c * 64;
      vf0[cb] = *(const bf16x8*)(Vr + quad * 8);
      vf1[cb] = *(const bf16x8*)(Vr + 32 + quad * 8);
    }
    // shared K fragments -> scores for both subtiles
    f32x4 sa[2][4];
#pragma unroll
    for (int cb = 0; cb < 4; ++cb) {
      const unsigned short* Kr = K + (size_t)(c * 64 + cb * 16 + l16) * DK_;
      const bf16x8 kf0 = *(const bf16x8*)(Kr + quad * 8);
      const bf16x8 kf1 = *(const bf16x8*)(Kr + 32 + quad * 8);
      f32x4 s0 = {0.f, 0.f, 0.f, 0.f}, s1 = {0.f, 0.f, 0.f, 0.f};
      s0 = __builtin_amdgcn_mfma_f32_16x16x32_bf16(qfa0, kf0, s0, 0, 0, 0);
      s0 = __builtin_amdgcn_mfma_f32_16x16x32_bf16(qfa1, kf1, s0, 0, 0, 0);
      s1 = __builtin_amdgcn_mfma_f32_16x16x32_bf16(qfb0, kf0, s1, 0, 0, 0);
      s1 = __builtin_amdgcn_mfma_f32_16x16x32_bf16(qfb1, kf1, s1, 0, 0, 0);
      sa[0][cb] = s0; sa[1][cb] = s1;
    }
    if (last) {
#pragma unroll
      for (int cb = 0; cb < 4; ++cb) {
        const int key = c * 64 + cb * 16 + l16;
#pragma unroll
        for (int r = 0; r < 4; ++r) {
          if (key > (myrow0 + r)) sa[0][cb][r] = -1e30f;
          if (key > (myrow1 + r)) sa[1][cb][r] = -1e30f;
        }
      }
    }

#pragma unroll
    for (int t = 0; t < 2; ++t) {
      const int rowbase = t ? myrow1 : myrow0;
#pragma unroll
      for (int r = 0; r < 4; ++r) {
        float v0 = scan16(__expf(sa[t][0][r]));
        float v1 = scan16(__expf(sa[t][1][r]));
        float v2 = scan16(__expf(sa[t][2][r]));
        float v3 = scan16(__expf(sa[t][3][r]));
        const float tt0 = bcast15(v0), tt1 = bcast15(v1);
        const float tt2 = bcast15(v2), tt3 = bcast15(v3);
        const float base = carry[t][r];
        const float p01 = tt0 + tt1, p012 = p01 + tt2;
        const float iT = invT[t][r];
        const float cum0 = (base + v0) * iT;
        const float cum1 = (base + tt0 + v1) * iT;
        const float cum2 = (base + p01 + v2) * iT;
        const float cum3 = (base + p012 + v3) * iT;
        carry[t][r] = base + p012 + tt3;

        const float bpos = (float)(rowbase + r) - (float)(c * 64 + l16);
        float st0, st1, st2, st3;
        {
          float dd = sqrtf(fmaxf((1.f - cum0) * bpos, 0.f));
          st0 = sa[t][0][r] * fmaxf(__expf(dd * gv), 1e-5f);
          dd = sqrtf(fmaxf((1.f - cum1) * (bpos - 16.f), 0.f));
          st1 = sa[t][1][r] * fmaxf(__expf(dd * gv), 1e-5f);
          dd = sqrtf(fmaxf((1.f - cum2) * (bpos - 32.f), 0.f));
          st2 = sa[t][2][r] * fmaxf(__expf(dd * gv), 1e-5f);
          dd = sqrtf(fmaxf((1.f - cum3) * (bpos - 48.f), 0.f));
          st3 = sa[t][3][r] * fmaxf(__expf(dd * gv), 1e-5f);
        }

        const float w0 = __expf(st0), w1 = __expf(st1);
        const float w2 = __expf(st2), w3 = __expf(st3);
        l2a[t][r] += (w0 + w1) + (w2 + w3);
        const int prow = t * 16 + quad * 4 + r;
        Ps[prow][ 0 + l16] = f2bf(w0);
        Ps[prow][16 + l16] = f2bf(w1);
        Ps[prow][32 + l16] = f2bf(w2);
        Ps[prow][48 + l16] = f2bf(w3);
      }
    }
    asm volatile("s_waitcnt lgkmcnt(0)" ::: "memory");  // wave-private Ps

    const bf16x8 pfa0 = *(const bf16x8*)&Ps[l16][quad * 8];
    const bf16x8 pfa1 = *(const bf16x8*)&Ps[l16][32 + quad * 8];
    const bf16x8 pfb0 = *(const bf16x8*)&Ps[16 + l16][quad * 8];
    const bf16x8 pfb1 = *(const bf16x8*)&Ps[16 + l16][32 + quad * 8];
#pragma unroll
    for (int cb = 0; cb < 4; ++cb) {
      oacc[0][cb] = __builtin_amdgcn_mfma_f32_16x16x32_bf16(pfa0, vf0[cb], oacc[0][cb], 0, 0, 0);
      oacc[0][cb] = __builtin_amdgcn_mfma_f32_16x16x32_bf16(pfa1, vf1[cb], oacc[0][cb], 0, 0, 0);
      oacc[1][cb] = __builtin_amdgcn_mfma_f32_16x16x32_bf16(pfb0, vf0[cb], oacc[1][cb], 0, 0, 0);
      oacc[1][cb] = __builtin_amdgcn_mfma_f32_16x16x32_bf16(pfb1, vf1[cb], oacc[1][cb], 0, 0, 0);
    }
  }

  // ===== epilogue: normalize + store both subtiles =====
#pragma unroll
  for (int t = 0; t < 2; ++t) {
    const int rowbase = t ? myrow1 : myrow0;
#pragma unroll
    for (int r = 0; r < 4; ++r) {
      const float inv = 1.f / red16(l2a[t][r]);
      const size_t base = ((size_t)b * S_ + rowbase + r) * D_ + h * DK_;
      O[base +  0 + l16] = f2bf(oacc[t][0][r] * inv);
      O[base + 16 + l16] = f2bf(oacc[t][1][r] * inv);
      O[base + 32 + l16] = f2bf(oacc[t][2][r] * inv);
      O[base + 48 + l16] = f2bf(oacc[t][3][r] * inv);
    }
  }
}

// ---------------------------------------------------------------------------
// Launch. Q tensors (z=0,3) pre-scaled by 1/8 in proj epilogue.
// ---------------------------------------------------------------------------
extern "C" void kernel_launch(void* const* d_in, const int* in_sizes, int n_in,
                              void* d_out, int out_size, void* d_ws, size_t ws_size,
                              hipStream_t stream) {
  const float* query_mean  = (const float*)d_in[0];
  const float* query_cov   = (const float*)d_in[1];
  const float* key_mean    = (const float*)d_in[2];
  const float* key_cov     = (const float*)d_in[3];
  const float* values_mean = (const float*)d_in[4];
  const float* values_cov  = (const float*)d_in[5];
  const float* Wk_mean = (const float*)d_in[6];
  const float* bk_mean = (const float*)d_in[7];
  const float* Wk_cov  = (const float*)d_in[8];
  const float* bk_cov  = (const float*)d_in[9];
  const float* Wv_mean = (const float*)d_in[10];
  const float* bv_mean = (const float*)d_in[11];
  const float* Wv_cov  = (const float*)d_in[12];
  const float* bv_cov  = (const float*)d_in[13];
  const float* Wo_mean = (const float*)d_in[14];
  const float* bo_mean = (const float*)d_in[15];
  const float* Wo_cov  = (const float*)d_in[16];
  const float* bo_cov  = (const float*)d_in[17];
  const float* gammas  = (const float*)d_in[18];

  unsigned short* qkv  = (unsigned short*)d_ws;
  unsigned short* obuf = qkv + 6 * SZ_;
  unsigned short* Wt4  = (unsigned short*)d_out;       // d_out as scratch
  unsigned short* Wot  = qkv + 2 * SZ_;                // V^T-mean slot, dead after attn
  float* out = (float*)d_out;

  TpArgs t1;
  t1.W[0] = Wk_mean; t1.W[1] = Wv_mean; t1.W[2] = Wk_cov; t1.W[3] = Wv_cov;
  for (int i = 0; i < 4; ++i) t1.out[i] = Wt4 + (size_t)i * WSZ_;
  wtrans<<<dim3(64, 1, 4), 256, 0, stream>>>(t1);

  ProjArgs pa;
  const float* pA[6] = {query_mean, key_mean, values_mean, query_cov, key_cov, values_cov};
  const int   wIdx[6] = {0, 0, 1, 2, 2, 3};
  const float* pb[6] = {bk_mean, bk_mean, bv_mean, bk_cov, bk_cov, bv_cov};
  const int pv[6] = {0, 0, 1, 0, 0, 1};
  const float ps[6] = {0.125f, 1.f, 1.f, 0.125f, 1.f, 1.f};  // fold 1/sqrt(DK) into Q
  for (int i = 0; i < 6; ++i) {
    pa.A[i] = pA[i]; pa.Wt[i] = Wt4 + (size_t)wIdx[i] * WSZ_; pa.bias[i] = pb[i];
    pa.out[i] = qkv + (size_t)i * SZ_; pa.vmode[i] = pv[i]; pa.scale[i] = ps[i];
  }
  proj_mfma<<<dim3(4, 32, 6), 256, 0, stream>>>(pa);

  attn_mfma<<<dim3(32, 32, 2), 64, 0, stream>>>(qkv, gammas, obuf);

  TpArgs t2;
  t2.W[0] = Wo_mean; t2.W[1] = Wo_cov; t2.W[2] = Wo_mean; t2.W[3] = Wo_cov;
  t2.out[0] = Wot; t2.out[1] = Wot + WSZ_; t2.out[2] = Wot; t2.out[3] = Wot + WSZ_;
  wtrans<<<dim3(64, 1, 2), 256, 0, stream>>>(t2);

  OutArgs oa;
  oa.A[0] = obuf;        oa.A[1] = obuf + SZ_;
  oa.Wt[0] = Wot;        oa.Wt[1] = Wot + WSZ_;
  oa.bias[0] = bo_mean;  oa.bias[1] = bo_cov;
  oa.out[0] = out;       oa.out[1] = out + (size_t)MROWS_ * D_;
  out_mfma<<<dim3(4, 32, 2), 256, 0, stream>>>(oa);
}

// Round 9
// 296.433 us; speedup vs baseline: 1.0467x; 1.0467x over previous
//
#include <hip/hip_runtime.h>
#include <hip/hip_bf16.h>
#include <math.h>

constexpr int B_  = 4;
constexpr int S_  = 1024;
constexpr int D_  = 512;
constexpr int H_  = 8;
constexpr int DK_ = 64;
constexpr int MROWS_ = B_ * S_;          // 4096
constexpr size_t SZ_ = (size_t)B_ * H_ * S_ * DK_;  // 2M elems per tensor
constexpr size_t WSZ_ = (size_t)D_ * D_;            // 256K elems per weight

typedef __attribute__((ext_vector_type(8))) short bf16x8;
typedef __attribute__((ext_vector_type(4))) float f32x4;

__device__ __forceinline__ float bf2f(unsigned short u) {
  union { unsigned int u; float f; } v; v.u = (unsigned int)u << 16; return v.f;
}
__device__ __forceinline__ unsigned short f2bf(float f) {
  union { float f; unsigned int u; } v; v.f = f;
  unsigned int r = v.u + 0x7FFFu + ((v.u >> 16) & 1u);   // RNE
  return (unsigned short)(r >> 16);
}

// ---- DPP cross-lane helpers ----
template <int CTRL>
__device__ __forceinline__ float dpp_mov_f(float x) {
  return __builtin_bit_cast(float,
      __builtin_amdgcn_update_dpp(0, __builtin_bit_cast(int, x), CTRL, 0xF, 0xF, true));
}
__device__ __forceinline__ float scan16(float v) {
  v += dpp_mov_f<0x111>(v);   // row_shr:1
  v += dpp_mov_f<0x112>(v);   // row_shr:2
  v += dpp_mov_f<0x114>(v);   // row_shr:4
  v += dpp_mov_f<0x118>(v);   // row_shr:8
  return v;
}
__device__ __forceinline__ float red16(float v) {
  v += dpp_mov_f<0x128>(v);   // row_ror:8
  v += dpp_mov_f<0x124>(v);   // row_ror:4
  v += dpp_mov_f<0x122>(v);   // row_ror:2
  v += dpp_mov_f<0x121>(v);   // row_ror:1
  return v;
}
__device__ __forceinline__ float bcast15(float v) {
  return __builtin_bit_cast(float,
      __builtin_amdgcn_ds_swizzle(__builtin_bit_cast(int, v), 0x01F0));
}

// ---------------------------------------------------------------------------
// W transpose+convert (unchanged).
// ---------------------------------------------------------------------------
struct TpArgs { const float* W[4]; unsigned short* out[4]; };

__global__ __launch_bounds__(256) void wtrans(TpArgs a) {
  const int z = blockIdx.z;
  const float* __restrict__ W = a.W[z];
  unsigned short* __restrict__ out = a.out[z];
  __shared__ float T[64][65];
  const int tid = threadIdx.x;
  const int tx = blockIdx.x & 7, ty = blockIdx.x >> 3;
  const int k0 = ty * 64, n0 = tx * 64;
#pragma unroll
  for (int i = 0; i < 4; ++i) {
    const int idx = tid + i * 256;
    const int r = idx >> 4, c4 = (idx & 15) * 4;
    const float4 w = *(const float4*)&W[(size_t)(k0 + r) * D_ + n0 + c4];
    T[r][c4 + 0] = w.x; T[r][c4 + 1] = w.y; T[r][c4 + 2] = w.z; T[r][c4 + 3] = w.w;
  }
  __syncthreads();
#pragma unroll
  for (int i = 0; i < 4; ++i) {
    const int idx = tid + i * 256;
    const int n = idx >> 4, kc = (idx & 15) * 4;
    ushort4 pk;
    pk.x = f2bf(T[kc + 0][n]); pk.y = f2bf(T[kc + 1][n]);
    pk.z = f2bf(T[kc + 2][n]); pk.w = f2bf(T[kc + 3][n]);
    *(ushort4*)&out[(size_t)(n0 + n) * D_ + k0 + kc] = pk;
  }
}

// ---------------------------------------------------------------------------
// MFMA projection GEMM. scale folds 1/sqrt(DK) into Q; vmode=1 (V^T)
// epilogue LDS-transposes for coalesced 16B stores.
// ---------------------------------------------------------------------------
struct ProjArgs {
  const float* A[6]; const unsigned short* Wt[6]; const float* bias[6];
  unsigned short* out[6]; int vmode[6]; float scale[6];
};

__global__ __launch_bounds__(256) void proj_mfma(ProjArgs args) {
  const int z = blockIdx.z;
  const float* __restrict__ A = args.A[z];
  const unsigned short* __restrict__ Wt = args.Wt[z];
  const float* __restrict__ bias = args.bias[z];
  unsigned short* __restrict__ out = args.out[z];
  const int vmode = args.vmode[z];
  const float scale = args.scale[z];

  __shared__ unsigned short Abuf[128][40];
  __shared__ unsigned short Bbuf[128][40];
  const int tid = threadIdx.x, wv = tid >> 6, lane = tid & 63;
  const int quad = lane >> 4, l16 = lane & 15;
  const int wm = wv >> 1, wn = wv & 1;
  const int n0 = blockIdx.x * 128, m0 = blockIdx.y * 128;

  f32x4 acc[4][4];
#pragma unroll
  for (int i = 0; i < 4; ++i)
#pragma unroll
    for (int j = 0; j < 4; ++j) acc[i][j] = (f32x4){0.f, 0.f, 0.f, 0.f};

  for (int kt = 0; kt < 16; ++kt) {
    const int k0 = kt * 32;
    __syncthreads();
#pragma unroll
    for (int i = 0; i < 4; ++i) {
      const int idx = tid + i * 256;
      const int m = idx >> 3, c = idx & 7;
      const float4 av = *(const float4*)&A[(size_t)(m0 + m) * D_ + k0 + c * 4];
      ushort4 p;
      p.x = f2bf(av.x); p.y = f2bf(av.y); p.z = f2bf(av.z); p.w = f2bf(av.w);
      *(ushort4*)&Abuf[m][c * 4] = p;
    }
#pragma unroll
    for (int i = 0; i < 2; ++i) {
      const int idx = tid + i * 256;
      const int n = idx >> 2, c = idx & 3;
      *(uint4*)&Bbuf[n][c * 8] = *(const uint4*)&Wt[(size_t)(n0 + n) * D_ + k0 + c * 8];
    }
    __syncthreads();

    bf16x8 af[4], bfr[4];
#pragma unroll
    for (int i = 0; i < 4; ++i) af[i] = *(const bf16x8*)&Abuf[wm * 64 + i * 16 + l16][quad * 8];
#pragma unroll
    for (int j = 0; j < 4; ++j) bfr[j] = *(const bf16x8*)&Bbuf[wn * 64 + j * 16 + l16][quad * 8];
#pragma unroll
    for (int i = 0; i < 4; ++i)
#pragma unroll
      for (int j = 0; j < 4; ++j)
        acc[i][j] = __builtin_amdgcn_mfma_f32_16x16x32_bf16(af[i], bfr[j], acc[i][j], 0, 0, 0);
  }

  if (!vmode) {
#pragma unroll
    for (int j = 0; j < 4; ++j) {
      const int col = n0 + wn * 64 + j * 16 + l16;
      const float bv = bias[col];
      const int h = col >> 6, dk = col & 63;
#pragma unroll
      for (int i = 0; i < 4; ++i) {
        const int mbase = m0 + wm * 64 + i * 16 + quad * 4;
        const int b = mbase >> 10;
#pragma unroll
        for (int r = 0; r < 4; ++r) {
          const int s = (mbase + r) & 1023;
          out[(((size_t)b * H_ + h) * S_ + s) * DK_ + dk] = f2bf((acc[i][j][r] + bv) * scale);
        }
      }
    }
  } else {
    // V^T epilogue: LDS transpose (reuse Abuf) -> coalesced 16B stores.
    unsigned short (*Tb)[36] = (unsigned short (*)[36])&Abuf[0][0];  // [dk 128][s 32+pad]
    const int bb = m0 >> 10;          // tiles never straddle batches (1024%128==0)
    const int msub = m0 & 1023;       // sequence offset within batch (R8 bugfix)
    for (int i = 0; i < 4; ++i) {
      __syncthreads();
#pragma unroll
      for (int j = 0; j < 4; ++j) {
        const int col = n0 + wn * 64 + j * 16 + l16;
        const float bv = bias[col];
        const int dk_local = wn * 64 + j * 16 + l16;
        const int sidx = wm * 16 + quad * 4;
#pragma unroll
        for (int r = 0; r < 4; ++r)
          Tb[dk_local][sidx + r] = f2bf(acc[i][j][r] + bv);
      }
      __syncthreads();
      const int dkl = tid >> 1, sh = tid & 1;
      const int hh = (n0 + dkl) >> 6;
      const int dk = (n0 + dkl) & 63;
      const int s0 = msub + sh * 64 + i * 16;
      const size_t gbase = (((size_t)bb * H_ + hh) * DK_ + dk) * S_ + s0;
      *(uint4*)&out[gbase]     = *(const uint4*)&Tb[dkl][sh * 16];
      *(uint4*)&out[gbase + 8] = *(const uint4*)&Tb[dkl][sh * 16 + 8];
    }
  }
}

// ---------------------------------------------------------------------------
// MFMA output GEMM (unchanged).
// ---------------------------------------------------------------------------
struct OutArgs {
  const unsigned short* A[2]; const unsigned short* Wt[2];
  const float* bias[2]; float* out[2];
};

__global__ __launch_bounds__(256) void out_mfma(OutArgs args) {
  const int z = blockIdx.z;
  const unsigned short* __restrict__ A = args.A[z];
  const unsigned short* __restrict__ Wt = args.Wt[z];
  const float* __restrict__ bias = args.bias[z];
  float* __restrict__ out = args.out[z];

  __shared__ unsigned short Abuf[128][40];
  __shared__ unsigned short Bbuf[128][40];
  const int tid = threadIdx.x, wv = tid >> 6, lane = tid & 63;
  const int quad = lane >> 4, l16 = lane & 15;
  const int wm = wv >> 1, wn = wv & 1;
  const int n0 = blockIdx.x * 128, m0 = blockIdx.y * 128;

  f32x4 acc[4][4];
#pragma unroll
  for (int i = 0; i < 4; ++i)
#pragma unroll
    for (int j = 0; j < 4; ++j) acc[i][j] = (f32x4){0.f, 0.f, 0.f, 0.f};

  for (int kt = 0; kt < 16; ++kt) {
    const int k0 = kt * 32;
    __syncthreads();
#pragma unroll
    for (int i = 0; i < 2; ++i) {
      const int idx = tid + i * 256;
      const int m = idx >> 2, c = idx & 3;
      *(uint4*)&Abuf[m][c * 8] = *(const uint4*)&A[(size_t)(m0 + m) * D_ + k0 + c * 8];
    }
#pragma unroll
    for (int i = 0; i < 2; ++i) {
      const int idx = tid + i * 256;
      const int n = idx >> 2, c = idx & 3;
      *(uint4*)&Bbuf[n][c * 8] = *(const uint4*)&Wt[(size_t)(n0 + n) * D_ + k0 + c * 8];
    }
    __syncthreads();

    bf16x8 af[4], bfr[4];
#pragma unroll
    for (int i = 0; i < 4; ++i) af[i] = *(const bf16x8*)&Abuf[wm * 64 + i * 16 + l16][quad * 8];
#pragma unroll
    for (int j = 0; j < 4; ++j) bfr[j] = *(const bf16x8*)&Bbuf[wn * 64 + j * 16 + l16][quad * 8];
#pragma unroll
    for (int i = 0; i < 4; ++i)
#pragma unroll
      for (int j = 0; j < 4; ++j)
        acc[i][j] = __builtin_amdgcn_mfma_f32_16x16x32_bf16(af[i], bfr[j], acc[i][j], 0, 0, 0);
  }

#pragma unroll
  for (int j = 0; j < 4; ++j) {
    const int col = n0 + wn * 64 + j * 16 + l16;
    const float bv = bias[col];
#pragma unroll
    for (int i = 0; i < 4; ++i) {
      const int mbase = m0 + wm * 64 + i * 16 + quad * 4;
#pragma unroll
      for (int r = 0; r < 4; ++r)
        out[(size_t)(mbase + r) * D_ + col] = acc[i][j][r] + bv;
    }
  }
}

// ---------------------------------------------------------------------------
// R9 attention (= R8): R4 structure + balanced bh-pairing.
// Block = 512 thr (8 waves): waves 0-3 = (bh_even, qt) subtiles, waves 4-7 =
// (bh_odd, SAME qt) -> all 8 waves identical duration. K/V shared 4-way per
// half. Barrier-free, DPP scans, no-max softmax, Q pre-scaled by 1/8.
// Grid (pair=16, qt=16 heavy-first, ch=2) = 512 blocks.
// ---------------------------------------------------------------------------
__global__ __launch_bounds__(512) void attn_mfma(
    const unsigned short* __restrict__ qkv, const float* __restrict__ gammas,
    unsigned short* __restrict__ Obase)
{
  __shared__ unsigned short Ps[8][16][72];   // per-wave P relayout tile

  const int tid = threadIdx.x;
  const int w = tid >> 6, lane = tid & 63, quad = lane >> 4, l16 = lane & 15;
  const int qt = 15 - blockIdx.y;            // heavy first
  const int bh = (blockIdx.x << 1) + (w >> 2);
  const int ch = blockIdx.z;
  const int wq = w & 3;
  const int q0 = qt << 6;
  const int b = bh >> 3, h = bh & 7;

  const unsigned short* Q  = qkv + (size_t)ch * 3 * SZ_ + (size_t)bh * S_ * DK_;
  const unsigned short* K  = qkv + (size_t)ch * 3 * SZ_ + SZ_ + (size_t)bh * S_ * DK_;
  const unsigned short* Vt = qkv + (size_t)ch * 3 * SZ_ + 2 * SZ_ + (size_t)bh * (size_t)DK_ * S_;
  unsigned short* O = Obase + (size_t)ch * SZ_;

  const float g = gammas[h];
  const float gv = -(fmaxf(g, 0.f) + log1pf(__expf(-fabsf(g))));  // -softplus

  // Q fragments (pre-scaled by 1/8 in proj)
  const unsigned short* Qrow = Q + (size_t)(q0 + wq * 16 + l16) * DK_;
  const bf16x8 qf0 = *(const bf16x8*)(Qrow + quad * 8);
  const bf16x8 qf1 = *(const bf16x8*)(Qrow + 32 + quad * 8);
  const int myrow = q0 + wq * 16 + quad * 4;   // + r

  // ===================== pass A: T = sum exp(s) =====================
  float Tacc[4] = {0.f, 0.f, 0.f, 0.f};
  for (int kt = 0; kt <= qt; ++kt) {
    f32x4 sa[4];
#pragma unroll
    for (int cb = 0; cb < 4; ++cb) {
      const unsigned short* Kr = K + (size_t)(kt * 64 + cb * 16 + l16) * DK_;
      const bf16x8 kf0 = *(const bf16x8*)(Kr + quad * 8);
      const bf16x8 kf1 = *(const bf16x8*)(Kr + 32 + quad * 8);
      f32x4 a = {0.f, 0.f, 0.f, 0.f};
      a = __builtin_amdgcn_mfma_f32_16x16x32_bf16(qf0, kf0, a, 0, 0, 0);
      a = __builtin_amdgcn_mfma_f32_16x16x32_bf16(qf1, kf1, a, 0, 0, 0);
      sa[cb] = a;
    }
    if (kt == qt) {
#pragma unroll
      for (int cb = 0; cb < 4; ++cb)
#pragma unroll
        for (int r = 0; r < 4; ++r) {
          float e = __expf(sa[cb][r]);
          if ((kt * 64 + cb * 16 + l16) > (myrow + r)) e = 0.f;
          Tacc[r] += e;
        }
    } else {
#pragma unroll
      for (int cb = 0; cb < 4; ++cb)
#pragma unroll
        for (int r = 0; r < 4; ++r)
          Tacc[r] += __expf(sa[cb][r]);
    }
  }
  float invT[4];
#pragma unroll
  for (int r = 0; r < 4; ++r) invT[r] = 1.f / red16(Tacc[r]);

  // ===================== pass B =====================
  float carry[4] = {0.f, 0.f, 0.f, 0.f};
  float l2a[4] = {0.f, 0.f, 0.f, 0.f};
  f32x4 oacc[4];
#pragma unroll
  for (int cb = 0; cb < 4; ++cb) oacc[cb] = (f32x4){0.f, 0.f, 0.f, 0.f};

  for (int kt = 0; kt <= qt; ++kt) {
    // V fragments first: consumed at end of iteration
    bf16x8 vf0[4], vf1[4];
#pragma unroll
    for (int cb = 0; cb < 4; ++cb) {
      const unsigned short* Vr = Vt + (size_t)(cb * 16 + l16) * S_ + kt * 64;
      vf0[cb] = *(const bf16x8*)(Vr + quad * 8);
      vf1[cb] = *(const bf16x8*)(Vr + 32 + quad * 8);
    }

    f32x4 sa[4];
#pragma unroll
    for (int cb = 0; cb < 4; ++cb) {
      const unsigned short* Kr = K + (size_t)(kt * 64 + cb * 16 + l16) * DK_;
      const bf16x8 kf0 = *(const bf16x8*)(Kr + quad * 8);
      const bf16x8 kf1 = *(const bf16x8*)(Kr + 32 + quad * 8);
      f32x4 a = {0.f, 0.f, 0.f, 0.f};
      a = __builtin_amdgcn_mfma_f32_16x16x32_bf16(qf0, kf0, a, 0, 0, 0);
      a = __builtin_amdgcn_mfma_f32_16x16x32_bf16(qf1, kf1, a, 0, 0, 0);
      sa[cb] = a;
    }
    if (kt == qt) {
#pragma unroll
      for (int cb = 0; cb < 4; ++cb)
#pragma unroll
        for (int r = 0; r < 4; ++r)
          if ((kt * 64 + cb * 16 + l16) > (myrow + r)) sa[cb][r] = -1e30f;
    }

#pragma unroll
    for (int r = 0; r < 4; ++r) {
      float v0 = scan16(__expf(sa[0][r]));
      float v1 = scan16(__expf(sa[1][r]));
      float v2 = scan16(__expf(sa[2][r]));
      float v3 = scan16(__expf(sa[3][r]));
      const float tt0 = bcast15(v0), tt1 = bcast15(v1);
      const float tt2 = bcast15(v2), tt3 = bcast15(v3);
      const float base = carry[r];
      const float p01 = tt0 + tt1, p012 = p01 + tt2;
      const float cum0 = (base + v0) * invT[r];
      const float cum1 = (base + tt0 + v1) * invT[r];
      const float cum2 = (base + p01 + v2) * invT[r];
      const float cum3 = (base + p012 + v3) * invT[r];
      carry[r] = base + p012 + tt3;

      const float bpos = (float)(myrow + r) - (float)(kt * 64 + l16);
      float st0, st1, st2, st3;
      {
        float dd = sqrtf(fmaxf((1.f - cum0) * bpos, 0.f));
        st0 = sa[0][r] * fmaxf(__expf(dd * gv), 1e-5f);
        dd = sqrtf(fmaxf((1.f - cum1) * (bpos - 16.f), 0.f));
        st1 = sa[1][r] * fmaxf(__expf(dd * gv), 1e-5f);
        dd = sqrtf(fmaxf((1.f - cum2) * (bpos - 32.f), 0.f));
        st2 = sa[2][r] * fmaxf(__expf(dd * gv), 1e-5f);
        dd = sqrtf(fmaxf((1.f - cum3) * (bpos - 48.f), 0.f));
        st3 = sa[3][r] * fmaxf(__expf(dd * gv), 1e-5f);
      }

      const float w0 = __expf(st0), w1 = __expf(st1);
      const float w2 = __expf(st2), w3 = __expf(st3);
      l2a[r] += (w0 + w1) + (w2 + w3);
      const int prow = quad * 4 + r;
      Ps[w][prow][ 0 + l16] = f2bf(w0);
      Ps[w][prow][16 + l16] = f2bf(w1);
      Ps[w][prow][32 + l16] = f2bf(w2);
      Ps[w][prow][48 + l16] = f2bf(w3);
    }
    asm volatile("s_waitcnt lgkmcnt(0)" ::: "memory");  // wave-private Ps

    const bf16x8 pf0 = *(const bf16x8*)&Ps[w][l16][quad * 8];
    const bf16x8 pf1 = *(const bf16x8*)&Ps[w][l16][32 + quad * 8];
#pragma unroll
    for (int cb = 0; cb < 4; ++cb) {
      oacc[cb] = __builtin_amdgcn_mfma_f32_16x16x32_bf16(pf0, vf0[cb], oacc[cb], 0, 0, 0);
      oacc[cb] = __builtin_amdgcn_mfma_f32_16x16x32_bf16(pf1, vf1[cb], oacc[cb], 0, 0, 0);
    }
  }

  // ---- epilogue ----
#pragma unroll
  for (int r = 0; r < 4; ++r) {
    const float inv = 1.f / red16(l2a[r]);
    const int srow = myrow + r;
    const size_t base = ((size_t)b * S_ + srow) * D_ + h * DK_;
    O[base +  0 + l16] = f2bf(oacc[0][r] * inv);
    O[base + 16 + l16] = f2bf(oacc[1][r] * inv);
    O[base + 32 + l16] = f2bf(oacc[2][r] * inv);
    O[base + 48 + l16] = f2bf(oacc[3][r] * inv);
  }
}

// ---------------------------------------------------------------------------
// Launch.
// ---------------------------------------------------------------------------
extern "C" void kernel_launch(void* const* d_in, const int* in_sizes, int n_in,
                              void* d_out, int out_size, void* d_ws, size_t ws_size,
                              hipStream_t stream) {
  const float* query_mean  = (const float*)d_in[0];
  const float* query_cov   = (const float*)d_in[1];
  const float* key_mean    = (const float*)d_in[2];
  const float* key_cov     = (const float*)d_in[3];
  const float* values_mean = (const float*)d_in[4];
  const float* values_cov  = (const float*)d_in[5];
  const float* Wk_mean = (const float*)d_in[6];
  const float* bk_mean = (const float*)d_in[7];
  const float* Wk_cov  = (const float*)d_in[8];
  const float* bk_cov  = (const float*)d_in[9];
  const float* Wv_mean = (const float*)d_in[10];
  const float* bv_mean = (const float*)d_in[11];
  const float* Wv_cov  = (const float*)d_in[12];
  const float* bv_cov  = (const float*)d_in[13];
  const float* Wo_mean = (const float*)d_in[14];
  const float* bo_mean = (const float*)d_in[15];
  const float* Wo_cov  = (const float*)d_in[16];
  const float* bo_cov  = (const float*)d_in[17];
  const float* gammas  = (const float*)d_in[18];

  unsigned short* qkv  = (unsigned short*)d_ws;
  unsigned short* obuf = qkv + 6 * SZ_;
  unsigned short* Wt4  = (unsigned short*)d_out;       // d_out as scratch
  unsigned short* Wot  = qkv + 2 * SZ_;                // V^T-mean slot, dead after attn
  float* out = (float*)d_out;

  TpArgs t1;
  t1.W[0] = Wk_mean; t1.W[1] = Wv_mean; t1.W[2] = Wk_cov; t1.W[3] = Wv_cov;
  for (int i = 0; i < 4; ++i) t1.out[i] = Wt4 + (size_t)i * WSZ_;
  wtrans<<<dim3(64, 1, 4), 256, 0, stream>>>(t1);

  ProjArgs pa;
  const float* pA[6] = {query_mean, key_mean, values_mean, query_cov, key_cov, values_cov};
  const int   wIdx[6] = {0, 0, 1, 2, 2, 3};
  const float* pb[6] = {bk_mean, bk_mean, bv_mean, bk_cov, bk_cov, bv_cov};
  const int pv[6] = {0, 0, 1, 0, 0, 1};
  const float ps[6] = {0.125f, 1.f, 1.f, 0.125f, 1.f, 1.f};  // fold 1/sqrt(DK) into Q
  for (int i = 0; i < 6; ++i) {
    pa.A[i] = pA[i]; pa.Wt[i] = Wt4 + (size_t)wIdx[i] * WSZ_; pa.bias[i] = pb[i];
    pa.out[i] = qkv + (size_t)i * SZ_; pa.vmode[i] = pv[i]; pa.scale[i] = ps[i];
  }
  proj_mfma<<<dim3(4, 32, 6), 256, 0, stream>>>(pa);

  attn_mfma<<<dim3(16, 16, 2), 512, 0, stream>>>(qkv, gammas, obuf);

  TpArgs t2;
  t2.W[0] = Wo_mean; t2.W[1] = Wo_cov; t2.W[2] = Wo_mean; t2.W[3] = Wo_cov;
  t2.out[0] = Wot; t2.out[1] = Wot + WSZ_; t2.out[2] = Wot; t2.out[3] = Wot + WSZ_;
  wtrans<<<dim3(64, 1, 2), 256, 0, stream>>>(t2);

  OutArgs oa;
  oa.A[0] = obuf;        oa.A[1] = obuf + SZ_;
  oa.Wt[0] = Wot;        oa.Wt[1] = Wot + WSZ_;
  oa.bias[0] = bo_mean;  oa.bias[1] = bo_cov;
  oa.out[0] = out;       oa.out[1] = out + (size_t)MROWS_ * D_;
  out_mfma<<<dim3(4, 32, 2), 256, 0, stream>>>(oa);
}